// Round 3
// baseline (6256.517 us; speedup 1.0000x reference)
//
#include <hip/hip_runtime.h>
#include <hip/hip_cooperative_groups.h>
#include <math.h>

namespace cg = cooperative_groups;

#define B 64
#define H 512
#define MAXN 512
#define U 512
#define MM 32
#define IN_SZ 543      // H + M - 1
#define DEC_STRIDE 544
#define GBLK 256

// ---- d_out layout (floats) ----
#define PTR_OFF 0
#define PTR_SZ (B*MAXN*MM)            // 1,048,576
#define CLOSS_OFF (PTR_OFF + PTR_SZ)  // 1,048,576
#define ENC_OFF (CLOSS_OFF + 1)       // 1,048,577  (NOT 16B aligned -> scalar access to enc)
#define ENC_SZ (B*MAXN*H)             // 16,777,216
#define ADJ_OFF (ENC_OFF + ENC_SZ)    // 17,825,793

// ---- ws layout (floats) ----
#define EP_OFF 0
#define EP_SZ (B*MAXN*U)              // 16,777,216
#define HID0_OFF (EP_OFF + EP_SZ)
#define HID1_OFF (HID0_OFF + B*H)
#define W2H_OFF  (HID1_OFF + B*H)
#define COV_OFF  (W2H_OFF + B*H)
#define SC_OFF   (COV_OFF + B*MAXN)
#define DEC_OFF  (SC_OFF + B*MAXN)
#define TH_OFF   (DEC_OFF + B*DEC_STRIDE)
#define CL_OFF   (TH_OFF + B*32)
#define OFFS_OFF (CL_OFF + 64)

__device__ __forceinline__ float tanh_fast(float x){
    float e = __builtin_amdgcn_exp2f(x * 2.885390081777927f);
    return 1.0f - 2.0f * __builtin_amdgcn_rcpf(e + 1.0f);
}

// ---------------- init ----------------
__global__ void k_init(float* __restrict__ ws, float* __restrict__ out,
                       const float* __restrict__ hg, const int* __restrict__ lengths){
    int gid = blockIdx.x*256 + threadIdx.x;
    int nth = gridDim.x*256;
    float* ptr = out + PTR_OFF;
    for (int i=gid;i<PTR_SZ;i+=nth) ptr[i]=0.f;
    float* dec = ws + DEC_OFF;
    for (int i=gid;i<B*DEC_STRIDE;i+=nth) dec[i]=0.f;
    float* cov = ws + COV_OFF;
    float* hid0 = ws + HID0_OFF;
    for (int i=gid;i<B*H;i+=nth){ cov[i]=0.f; hid0[i]=hg[i]; }
    if (gid<64) (ws+CL_OFF)[gid]=0.f;
    if (gid==0){
        int* offs=(int*)(ws+OFFS_OFF); int acc=0;
        for(int b=0;b<B;b++){ offs[b]=acc; acc+=lengths[b]; }
    }
}

// ---------------- gather enc ----------------
__global__ __launch_bounds__(256) void k_gather(const float* __restrict__ h,
        const int* __restrict__ lengths, const float* __restrict__ offs_f,
        float* __restrict__ enc){
    const int* offs = (const int*)offs_f;
    int t = threadIdx.x;
    int row = blockIdx.x*2 + (t>>7);
    int c = (t&127)*4;
    int b = row >> 9, n = row & 511;
    int len = lengths[b];
    float4 v = make_float4(0.f,0.f,0.f,0.f);
    if (n < len){
        const float* p = h + (size_t)(offs[b]+n)*H + c;
        v = *(const float4*)p;
    }
    float* q = enc + (size_t)row*H + c;
    q[0]=v.x; q[1]=v.y; q[2]=v.z; q[3]=v.w;
}

// ---------------- ep = enc @ W1^T, fp32 tiled 128x128 ----------------
__global__ __launch_bounds__(256) void k_gemm_ep(const float* __restrict__ enc,
        const float* __restrict__ W1, float* __restrict__ ep){
    __shared__ float As[16][132];
    __shared__ float Bs[16][132];
    int tid = threadIdx.x;
    int bm = blockIdx.x >> 2, bn = blockIdx.x & 3;
    int r0 = bm*128, u0 = bn*128;
    int ty = tid >> 4, tx = tid & 15;
    float acc[8][8];
#pragma unroll
    for (int i=0;i<8;i++){
#pragma unroll
        for(int j=0;j<8;j++) acc[i][j]=0.f;
    }
    for (int k0=0;k0<512;k0+=16){
#pragma unroll
        for (int it=0; it<8; ++it){
            int idx = tid + it*256;
            int row = idx >> 4, k = idx & 15;
            As[k][row] = enc[(size_t)(r0+row)*512 + k0 + k];
        }
#pragma unroll
        for (int it=0; it<2; ++it){
            int idx = tid + it*256;
            int nn = idx >> 2, c = idx & 3;
            float4 v = *(const float4*)&W1[(size_t)(u0+nn)*512 + k0 + c*4];
            Bs[c*4+0][nn]=v.x; Bs[c*4+1][nn]=v.y; Bs[c*4+2][nn]=v.z; Bs[c*4+3][nn]=v.w;
        }
        __syncthreads();
#pragma unroll
        for (int k=0;k<16;k++){
            float4 a0 = *(const float4*)&As[k][ty*8];
            float4 a1 = *(const float4*)&As[k][ty*8+4];
            float4 b0 = *(const float4*)&Bs[k][tx*4];
            float4 b1 = *(const float4*)&Bs[k][64+tx*4];
            float a[8]={a0.x,a0.y,a0.z,a0.w,a1.x,a1.y,a1.z,a1.w};
            float bb[8]={b0.x,b0.y,b0.z,b0.w,b1.x,b1.y,b1.z,b1.w};
#pragma unroll
            for(int im=0;im<8;im++){
#pragma unroll
                for(int jn=0;jn<8;jn++) acc[im][jn] += a[im]*bb[jn];
            }
        }
        __syncthreads();
    }
#pragma unroll
    for (int im=0;im<8;im++){
        int r = r0 + ty*8 + im;
        float4 v0 = make_float4(acc[im][0],acc[im][1],acc[im][2],acc[im][3]);
        float4 v1 = make_float4(acc[im][4],acc[im][5],acc[im][6],acc[im][7]);
        *(float4*)&ep[(size_t)r*512 + u0 + tx*4] = v0;
        *(float4*)&ep[(size_t)r*512 + u0 + 64 + tx*4] = v1;
    }
}

// ================= standalone per-step kernels (fallback path, proven in R1) =================
__global__ __launch_bounds__(256) void k_gru(const float* __restrict__ dec_in,
        const float* __restrict__ hid_in, float* __restrict__ hid_out,
        const float* __restrict__ w_ih, const float* __restrict__ w_hh,
        const float* __restrict__ b_ih, const float* __restrict__ b_hh){
    __shared__ float As[64][36];
    __shared__ float Ws[12][36];
    int tid=threadIdx.x; int b=tid&63; int q=tid>>6;
    int h0=blockIdx.x*4;
    float aI0=0,aI1=0,aI2=0,aH0=0,aH1=0,aH2=0;
    for (int k0=0;k0<IN_SZ;k0+=32){
        for (int it=0;it<2;it++){
            int idx=tid+it*256; int row=idx>>3, c=idx&7; int k=k0+c*4;
            float4 v=make_float4(0.f,0.f,0.f,0.f);
            const float* p=&dec_in[row*DEC_STRIDE+k];
            if (k+3 < IN_SZ) v=*(const float4*)p;
            else { if(k<IN_SZ)v.x=p[0]; if(k+1<IN_SZ)v.y=p[1]; if(k+2<IN_SZ)v.z=p[2]; }
            *(float4*)&As[row][c*4]=v;
        }
        if (tid<96){
            int rr=tid>>3,c=tid&7; int g=rr>>2,qq=rr&3;
            int j=h0+qq+512*g; int k=k0+c*4;
            float4 v=make_float4(0.f,0.f,0.f,0.f);
            const float* p=&w_ih[(size_t)j*IN_SZ+k];
            if(k<IN_SZ)v.x=p[0]; if(k+1<IN_SZ)v.y=p[1];
            if(k+2<IN_SZ)v.z=p[2]; if(k+3<IN_SZ)v.w=p[3];
            *(float4*)&Ws[rr][c*4]=v;
        }
        __syncthreads();
#pragma unroll
        for (int kk=0;kk<32;kk+=4){
            float4 a=*(const float4*)&As[b][kk];
            float4 w0=*(const float4*)&Ws[q][kk];
            float4 w1=*(const float4*)&Ws[4+q][kk];
            float4 w2=*(const float4*)&Ws[8+q][kk];
            aI0 += a.x*w0.x + a.y*w0.y + a.z*w0.z + a.w*w0.w;
            aI1 += a.x*w1.x + a.y*w1.y + a.z*w1.z + a.w*w1.w;
            aI2 += a.x*w2.x + a.y*w2.y + a.z*w2.z + a.w*w2.w;
        }
        __syncthreads();
    }
    for (int k0=0;k0<512;k0+=32){
        for (int it=0;it<2;it++){
            int idx=tid+it*256; int row=idx>>3,c=idx&7; int k=k0+c*4;
            *(float4*)&As[row][c*4] = *(const float4*)&hid_in[row*512+k];
        }
        if (tid<96){
            int rr=tid>>3,c=tid&7; int g=rr>>2,qq=rr&3;
            int j=h0+qq+512*g; int k=k0+c*4;
            *(float4*)&Ws[rr][c*4] = *(const float4*)&w_hh[(size_t)j*512+k];
        }
        __syncthreads();
#pragma unroll
        for (int kk=0;kk<32;kk+=4){
            float4 a=*(const float4*)&As[b][kk];
            float4 w0=*(const float4*)&Ws[q][kk];
            float4 w1=*(const float4*)&Ws[4+q][kk];
            float4 w2=*(const float4*)&Ws[8+q][kk];
            aH0 += a.x*w0.x + a.y*w0.y + a.z*w0.z + a.w*w0.w;
            aH1 += a.x*w1.x + a.y*w1.y + a.z*w1.z + a.w*w1.w;
            aH2 += a.x*w2.x + a.y*w2.y + a.z*w2.z + a.w*w2.w;
        }
        __syncthreads();
    }
    int h=h0+q;
    float gi0=aI0+b_ih[h], gi1=aI1+b_ih[h+512], gi2=aI2+b_ih[h+1024];
    float gh0=aH0+b_hh[h], gh1=aH1+b_hh[h+512], gh2=aH2+b_hh[h+1024];
    float r=1.f/(1.f+expf(-(gi0+gh0)));
    float z=1.f/(1.f+expf(-(gi1+gh1)));
    float nn=tanhf(gi2 + r*gh2);
    float hp=hid_in[b*512+h];
    hid_out[b*512+h]=(1.f-z)*nn+z*hp;
}

__global__ __launch_bounds__(256) void k_w2h_theta(const float* __restrict__ hid,
        const float* __restrict__ W2, const float* __restrict__ Wf, const float* __restrict__ bf,
        float* __restrict__ w2h, float* __restrict__ dec_in, float* __restrict__ adj, int step){
    __shared__ float As[64][36];
    __shared__ float Ws[4][36];
    int tid=threadIdx.x; int b=tid&63; int q=tid>>6;
    bool isTheta = blockIdx.x >= 128;
    int r0 = isTheta ? (int)(blockIdx.x-128)*4 : (int)blockIdx.x*4;
    const float* W = isTheta ? Wf : W2;
    int row = r0 + q;
    float acc=0.f;
    for (int k0=0;k0<512;k0+=32){
        for (int it=0;it<2;it++){
            int idx=tid+it*256; int rw=idx>>3,c=idx&7; int k=k0+c*4;
            *(float4*)&As[rw][c*4]=*(const float4*)&hid[rw*512+k];
        }
        if (tid<32){
            int rr=tid>>3,c=tid&7; int j=r0+rr; int k=k0+c*4;
            float4 v=make_float4(0.f,0.f,0.f,0.f);
            if (!isTheta || j<31) v=*(const float4*)&W[(size_t)j*512+k];
            *(float4*)&Ws[rr][c*4]=v;
        }
        __syncthreads();
#pragma unroll
        for(int kk=0;kk<32;kk+=4){
            float4 a=*(const float4*)&As[b][kk];
            float4 w=*(const float4*)&Ws[q][kk];
            acc += a.x*w.x+a.y*w.y+a.z*w.z+a.w*w.w;
        }
        __syncthreads();
    }
    if (!isTheta){
        w2h[b*512 + row] = acc;
    } else if (row < 31){
        float th = 1.f/(1.f+expf(-(acc + bf[row])));
        th = (row < step) ? th : 0.f;
        dec_in[b*DEC_STRIDE + 512 + row]=th;
        adj[b*992 + row*32 + step]=th;
    }
}

__global__ __launch_bounds__(256) void k_scores(const float* __restrict__ ep,
        const float* __restrict__ w2h, const float* __restrict__ cov,
        const float* __restrict__ wc, const float* __restrict__ v,
        const int* __restrict__ lengths, float* __restrict__ scores){
    __shared__ float sW[512], sV[512], sC[512];
    int b = blockIdx.x >> 7, chunk = blockIdx.x & 127;
    int n0 = chunk*4;
    int len = lengths[b];
    if (n0 >= len) return;
    int tid=threadIdx.x;
    for (int idx=tid; idx<384; idx+=256){
        int which = idx>>7, c = (idx&127)*4;
        float4 val;
        if (which==0) val=*(const float4*)&w2h[b*512+c];
        else if (which==1) val=*(const float4*)&v[c];
        else val=*(const float4*)&wc[c];
        float* dst = (which==0)?sW:((which==1)?sV:sC);
        *(float4*)&dst[c]=val;
    }
    __syncthreads();
    int wave=tid>>6, lane=tid&63;
    int n = n0 + wave;
    float cb = cov[b*512+n];
    const float4* row = (const float4*)&ep[(size_t)(b*512+n)*512];
    float acc=0.f;
#pragma unroll
    for (int kk=0;kk<2;kk++){
        int u4 = kk*64 + lane;
        float4 e=row[u4];
        float4 w=*(const float4*)&sW[u4*4];
        float4 cc=*(const float4*)&sC[u4*4];
        float4 vv=*(const float4*)&sV[u4*4];
        acc += tanh_fast(e.x + w.x + cb*cc.x)*vv.x;
        acc += tanh_fast(e.y + w.y + cb*cc.y)*vv.y;
        acc += tanh_fast(e.z + w.z + cb*cc.z)*vv.z;
        acc += tanh_fast(e.w + w.w + cb*cc.w)*vv.w;
    }
#pragma unroll
    for (int m=1;m<64;m<<=1) acc += __shfl_xor(acc, m, 64);
    if (lane==0) scores[b*512+n]=acc;
}

__global__ __launch_bounds__(512) void k_soft(const float* __restrict__ scores,
        const float* __restrict__ gum, const int* __restrict__ lengths,
        const float* __restrict__ enc, float* __restrict__ cov,
        float* __restrict__ dec_in, float* __restrict__ closs_b,
        float* __restrict__ pointer, int step){
    __shared__ float red[512];
    __shared__ int redi[512];
    int b=blockIdx.x, n=threadIdx.x;
    int len=lengths[b];
    float s = (n<len)? scores[b*512+n] : -1e30f;
    red[n]=s; __syncthreads();
    for(int o=256;o>=1;o>>=1){ if(n<o) red[n]=fmaxf(red[n],red[n+o]); __syncthreads(); }
    float mx=red[0]; __syncthreads();
    float e=(n<len)? expf(s-mx):0.f;
    red[n]=e; __syncthreads();
    for(int o=256;o>=1;o>>=1){ if(n<o) red[n]+=red[n+o]; __syncthreads(); }
    float Z=red[0]; __syncthreads();
    float att=e/Z;
    float c=cov[b*512+n];
    float cl=fminf(att,c);
    red[n]=cl; __syncthreads();
    for(int o=256;o>=1;o>>=1){ if(n<o) red[n]+=red[n+o]; __syncthreads(); }
    if(n==0) closs_b[b]+=red[0];
    __syncthreads();
    cov[b*512+n]=c+att;
    float lg=logf(att+1e-12f)+gum[((size_t)step*64+b)*512+n];
    red[n]=lg; redi[n]=n; __syncthreads();
    for(int o=256;o>=1;o>>=1){
        if(n<o){ if(red[n+o]>red[n]){red[n]=red[n+o];redi[n]=redi[n+o];} }
        __syncthreads();
    }
    int ns=redi[0];
    if(n==0) pointer[b*16384 + ns*32 + step]=1.f;
    dec_in[b*DEC_STRIDE+n]=enc[((size_t)b*512+ns)*512+n];
}

__global__ void k_final(const float* __restrict__ closs_b, float* __restrict__ out){
    if (threadIdx.x==0 && blockIdx.x==0){
        float s=0.f;
        for(int b=0;b<B;b++) s+=closs_b[b];
        out[CLOSS_OFF]=s/64.f;
    }
}

// ================= persistent cooperative loop kernel (fast path) =================
struct KParams {
    const float *gum, *W2, *wc, *v, *w_ih, *w_hh, *b_ih, *b_hh, *Wf, *bf;
    const int* lengths;
    float *enc, *pointer, *adj, *closs_out;
    float *ep, *hidA, *hidB, *w2h, *cov, *sc, *dec, *clb;
};

__global__ __launch_bounds__(256, 2) void k_loop(KParams P){
    cg::grid_group grid = cg::this_grid();
    __shared__ float As_s[64][36];   // 9216 B; reused as sW/sV/sC (C) and red (D)
    __shared__ float Ws_s[12][36];   // 1728 B; reused as redi (D)
    const int blk = blockIdx.x;
    const int tid = threadIdx.x;
    float* sbase = &As_s[0][0];
    float closs_acc = 0.f;

    for (int i=0; i<MM; ++i){
        const float* hin  = (i&1)? P.hidB : P.hidA;
        float*       hout = (i&1)? P.hidA : P.hidB;

        // ---- phase A: GRU (blocks 0..127) ----
        if (blk < 128){
            int b=tid&63, qg=tid>>6;
            int h0=blk*4;
            float aI0=0,aI1=0,aI2=0,aH0=0,aH1=0,aH2=0;
            for (int k0=0;k0<IN_SZ;k0+=32){
#pragma unroll
                for (int it=0;it<2;it++){
                    int idx=tid+it*256; int row=idx>>3, c=idx&7; int k=k0+c*4;
                    float4 vv=make_float4(0.f,0.f,0.f,0.f);
                    const float* p=&P.dec[row*DEC_STRIDE+k];
                    if (k+3 < IN_SZ) vv=*(const float4*)p;
                    else { if(k<IN_SZ)vv.x=p[0]; if(k+1<IN_SZ)vv.y=p[1]; if(k+2<IN_SZ)vv.z=p[2]; }
                    *(float4*)&As_s[row][c*4]=vv;
                }
                if (tid<96){
                    int rr=tid>>3,c=tid&7; int g=rr>>2,qq=rr&3;
                    int j=h0+qq+512*g; int k=k0+c*4;
                    float4 vv=make_float4(0.f,0.f,0.f,0.f);
                    const float* p=&P.w_ih[(size_t)j*IN_SZ+k];
                    if(k<IN_SZ)vv.x=p[0]; if(k+1<IN_SZ)vv.y=p[1];
                    if(k+2<IN_SZ)vv.z=p[2]; if(k+3<IN_SZ)vv.w=p[3];
                    *(float4*)&Ws_s[rr][c*4]=vv;
                }
                __syncthreads();
#pragma unroll
                for (int kk=0;kk<32;kk+=4){
                    float4 a=*(const float4*)&As_s[b][kk];
                    float4 w0=*(const float4*)&Ws_s[qg][kk];
                    float4 w1=*(const float4*)&Ws_s[4+qg][kk];
                    float4 w2=*(const float4*)&Ws_s[8+qg][kk];
                    aI0 += a.x*w0.x + a.y*w0.y + a.z*w0.z + a.w*w0.w;
                    aI1 += a.x*w1.x + a.y*w1.y + a.z*w1.z + a.w*w1.w;
                    aI2 += a.x*w2.x + a.y*w2.y + a.z*w2.z + a.w*w2.w;
                }
                __syncthreads();
            }
            for (int k0=0;k0<512;k0+=32){
#pragma unroll
                for (int it=0;it<2;it++){
                    int idx=tid+it*256; int row=idx>>3,c=idx&7; int k=k0+c*4;
                    *(float4*)&As_s[row][c*4] = *(const float4*)&hin[row*512+k];
                }
                if (tid<96){
                    int rr=tid>>3,c=tid&7; int g=rr>>2,qq=rr&3;
                    int j=h0+qq+512*g; int k=k0+c*4;
                    *(float4*)&Ws_s[rr][c*4] = *(const float4*)&P.w_hh[(size_t)j*512+k];
                }
                __syncthreads();
#pragma unroll
                for (int kk=0;kk<32;kk+=4){
                    float4 a=*(const float4*)&As_s[b][kk];
                    float4 w0=*(const float4*)&Ws_s[qg][kk];
                    float4 w1=*(const float4*)&Ws_s[4+qg][kk];
                    float4 w2=*(const float4*)&Ws_s[8+qg][kk];
                    aH0 += a.x*w0.x + a.y*w0.y + a.z*w0.z + a.w*w0.w;
                    aH1 += a.x*w1.x + a.y*w1.y + a.z*w1.z + a.w*w1.w;
                    aH2 += a.x*w2.x + a.y*w2.y + a.z*w2.z + a.w*w2.w;
                }
                __syncthreads();
            }
            int hh=h0+qg;
            float gi0=aI0+P.b_ih[hh], gi1=aI1+P.b_ih[hh+512], gi2=aI2+P.b_ih[hh+1024];
            float gh0=aH0+P.b_hh[hh], gh1=aH1+P.b_hh[hh+512], gh2=aH2+P.b_hh[hh+1024];
            float r=1.f/(1.f+expf(-(gi0+gh0)));
            float z=1.f/(1.f+expf(-(gi1+gh1)));
            float nn=tanhf(gi2 + r*gh2);
            float hp=hin[b*512+hh];
            hout[b*512+hh]=(1.f-z)*nn+z*hp;
        }
        grid.sync();

        // ---- phase B: w2h (blocks 0..127) + theta->dec tail/adj (128..135) ----
        if (blk < 136){
            int b=tid&63, qg=tid>>6;
            bool isTheta = blk >= 128;
            int r0 = isTheta ? (blk-128)*4 : blk*4;
            const float* W = isTheta ? P.Wf : P.W2;
            int row = r0 + qg;
            float acc=0.f;
            for (int k0=0;k0<512;k0+=32){
#pragma unroll
                for (int it=0;it<2;it++){
                    int idx=tid+it*256; int rw=idx>>3,c=idx&7; int k=k0+c*4;
                    *(float4*)&As_s[rw][c*4]=*(const float4*)&hout[rw*512+k];
                }
                if (tid<32){
                    int rr=tid>>3,c=tid&7; int j=r0+rr; int k=k0+c*4;
                    float4 vv=make_float4(0.f,0.f,0.f,0.f);
                    if (!isTheta || j<31) vv=*(const float4*)&W[(size_t)j*512+k];
                    *(float4*)&Ws_s[rr][c*4]=vv;
                }
                __syncthreads();
#pragma unroll
                for(int kk=0;kk<32;kk+=4){
                    float4 a=*(const float4*)&As_s[b][kk];
                    float4 w=*(const float4*)&Ws_s[qg][kk];
                    acc += a.x*w.x+a.y*w.y+a.z*w.z+a.w*w.w;
                }
                __syncthreads();
            }
            if (!isTheta){
                P.w2h[b*512 + row] = acc;
            } else if (row < 31){
                float th = 1.f/(1.f+expf(-(acc + P.bf[row])));
                th = (row < i) ? th : 0.f;
                P.dec[b*DEC_STRIDE + 512 + row] = th;
                P.adj[b*992 + row*32 + i] = th;
            }
        }
        grid.sync();

        // ---- phase C: scores (all 256 blocks; 4 blocks per b) ----
        {
            int b = blk >> 2, s = blk & 3;
            int len = P.lengths[b];
            int q = len >> 2;
            float* sW = sbase; float* sV = sbase+512; float* sC = sbase+1024;
            for (int idx=tid; idx<384; idx+=256){
                int which = idx>>7, c = (idx&127)*4;
                float4 val;
                if (which==0) val=*(const float4*)&P.w2h[b*512+c];
                else if (which==1) val=*(const float4*)&P.v[c];
                else val=*(const float4*)&P.wc[c];
                float* dst = (which==0)?sW:((which==1)?sV:sC);
                *(float4*)&dst[c]=val;
            }
            __syncthreads();
            int wave=tid>>6, lane=tid&63;
            for (int r=wave; r<q; r+=4){
                int n = s*q + r;
                float cb = P.cov[b*512+n];
                const float4* row4 = (const float4*)&P.ep[(size_t)(b*512+n)*512];
                float acc=0.f;
#pragma unroll
                for (int kk=0;kk<2;kk++){
                    int u4 = kk*64 + lane;
                    float4 e=row4[u4];
                    float4 w=*(const float4*)&sW[u4*4];
                    float4 cc=*(const float4*)&sC[u4*4];
                    float4 vv=*(const float4*)&sV[u4*4];
                    acc += tanh_fast(e.x + w.x + cb*cc.x)*vv.x;
                    acc += tanh_fast(e.y + w.y + cb*cc.y)*vv.y;
                    acc += tanh_fast(e.z + w.z + cb*cc.z)*vv.z;
                    acc += tanh_fast(e.w + w.w + cb*cc.w)*vv.w;
                }
#pragma unroll
                for (int m=1;m<64;m<<=1) acc += __shfl_xor(acc, m, 64);
                if (lane==0) P.sc[b*512+n]=acc;
            }
            __syncthreads();
        }
        grid.sync();

        // ---- phase D: softmax/cov/closs/argmax/dec head (blocks 0..63) ----
        if (blk < 64){
            int b = blk;
            int len = P.lengths[b];
            float* red = sbase;
            int* redi = (int*)&Ws_s[0][0];
            int n0=tid, n1=tid+256;
            float e0 = (n0<len)? expf(P.sc[b*512+n0]) : 0.f;
            float e1 = (n1<len)? expf(P.sc[b*512+n1]) : 0.f;
            red[tid]=e0+e1; __syncthreads();
            for(int o=128;o>=1;o>>=1){ if(tid<o) red[tid]+=red[tid+o]; __syncthreads(); }
            float Z=red[0]; __syncthreads();
            float a0=e0/Z, a1=e1/Z;
            float c0=P.cov[b*512+n0], c1=P.cov[b*512+n1];
            red[tid]=fminf(a0,c0)+fminf(a1,c1); __syncthreads();
            for(int o=128;o>=1;o>>=1){ if(tid<o) red[tid]+=red[tid+o]; __syncthreads(); }
            if(tid==0) closs_acc += red[0];
            __syncthreads();
            P.cov[b*512+n0]=c0+a0; P.cov[b*512+n1]=c1+a1;
            const float* gp = &P.gum[((size_t)i*64+b)*512];
            float lg0=logf(a0+1e-12f)+gp[n0];
            float lg1=logf(a1+1e-12f)+gp[n1];
            float lgm; int im;
            if (lg1>lg0){lgm=lg1;im=n1;} else {lgm=lg0;im=n0;}
            red[tid]=lgm; redi[tid]=im; __syncthreads();
            for(int o=128;o>=1;o>>=1){
                if(tid<o && red[tid+o]>red[tid]){red[tid]=red[tid+o];redi[tid]=redi[tid+o];}
                __syncthreads();
            }
            int ns=redi[0];
            if(tid==0) P.pointer[b*16384 + ns*32 + i]=1.f;
            const float* er=&P.enc[((size_t)b*512+ns)*512];
            P.dec[b*DEC_STRIDE+n0]=er[n0];
            P.dec[b*DEC_STRIDE+n1]=er[n1];
            __syncthreads();
        }
        grid.sync();
    }

    if (blk<64 && tid==0) P.clb[blk]=closs_acc;
    grid.sync();
    if (blk==0 && tid==0){
        float s=0.f;
        for(int b=0;b<B;b++) s+=P.clb[b];
        P.closs_out[0]=s/64.f;
    }
}

extern "C" void kernel_launch(void* const* d_in, const int* in_sizes, int n_in,
                              void* d_out, int out_size, void* d_ws, size_t ws_size,
                              hipStream_t stream){
    const float* h      = (const float*)d_in[0];
    const float* hg     = (const float*)d_in[1];
    const int*   lengths= (const int*)  d_in[2];
    const float* gumbel = (const float*)d_in[3];
    const float* W1     = (const float*)d_in[4];
    const float* W2     = (const float*)d_in[5];
    const float* wc     = (const float*)d_in[6];
    const float* v      = (const float*)d_in[7];
    const float* w_ih   = (const float*)d_in[8];
    const float* w_hh   = (const float*)d_in[9];
    const float* b_ih   = (const float*)d_in[10];
    const float* b_hh   = (const float*)d_in[11];
    const float* Wf     = (const float*)d_in[12];
    const float* bf     = (const float*)d_in[13];
    float* out = (float*)d_out;
    float* ws  = (float*)d_ws;
    float* enc = out + ENC_OFF;
    float* adj = out + ADJ_OFF;
    float* pointer = out + PTR_OFF;
    float* ep   = ws + EP_OFF;
    float* hidA = ws + HID0_OFF;
    float* hidB = ws + HID1_OFF;
    float* w2h  = ws + W2H_OFF;
    float* cov  = ws + COV_OFF;
    float* sc   = ws + SC_OFF;
    float* dec  = ws + DEC_OFF;
    float* clb  = ws + CL_OFF;

    hipLaunchKernelGGL(k_init,   dim3(512),  dim3(256), 0, stream, ws, out, hg, lengths);
    hipLaunchKernelGGL(k_gather, dim3(16384),dim3(256), 0, stream, h, lengths, ws+OFFS_OFF, enc);
    hipLaunchKernelGGL(k_gemm_ep,dim3(1024), dim3(256), 0, stream, enc, W1, ep);

    // decide cooperative capability deterministically (host-side queries only;
    // capture-safe: no stream/alloc/sync APIs)
    int dev = 0; (void)hipGetDevice(&dev);
    int coopAttr = 0;
    (void)hipDeviceGetAttribute(&coopAttr, hipDeviceAttributeCooperativeLaunch, dev);
    int nCU = 0;
    (void)hipDeviceGetAttribute(&nCU, hipDeviceAttributeMultiprocessorCount, dev);
    int maxBlkPerCU = 0;
    (void)hipOccupancyMaxActiveBlocksPerMultiprocessor(&maxBlkPerCU, (const void*)k_loop, 256, 0);
    bool useCoop = (coopAttr != 0) && ((long)maxBlkPerCU * (long)nCU >= GBLK);

    if (useCoop){
        KParams P;
        P.gum=gumbel; P.W2=W2; P.wc=wc; P.v=v; P.w_ih=w_ih; P.w_hh=w_hh;
        P.b_ih=b_ih; P.b_hh=b_hh; P.Wf=Wf; P.bf=bf; P.lengths=lengths;
        P.enc=enc; P.pointer=pointer; P.adj=adj; P.closs_out=out+CLOSS_OFF;
        P.ep=ep; P.hidA=hidA; P.hidB=hidB; P.w2h=w2h;
        P.cov=cov; P.sc=sc; P.dec=dec; P.clb=clb;
        void* args[] = { &P };
        hipError_t err = hipLaunchCooperativeKernel((void*)k_loop, dim3(GBLK), dim3(256),
                                                    args, 0, stream);
        if (err == hipSuccess) return;
        // fall through to the proven per-step path on any launch failure
    }

    for (int i=0;i<MM;i++){
        const float* hin = (i&1)? hidB : hidA;
        float*       hout= (i&1)? hidA : hidB;
        hipLaunchKernelGGL(k_gru,       dim3(128), dim3(256), 0, stream,
                           dec, hin, hout, w_ih, w_hh, b_ih, b_hh);
        hipLaunchKernelGGL(k_w2h_theta, dim3(136), dim3(256), 0, stream,
                           hout, W2, Wf, bf, w2h, dec, adj, i);
        hipLaunchKernelGGL(k_scores,    dim3(8192),dim3(256), 0, stream,
                           ep, w2h, cov, wc, v, lengths, sc);
        hipLaunchKernelGGL(k_soft,      dim3(64),  dim3(512), 0, stream,
                           sc, gumbel, lengths, enc, cov, dec, clb, pointer, i);
    }
    hipLaunchKernelGGL(k_final, dim3(1), dim3(64), 0, stream, clb, out);
}

// Round 4
// 3229.172 us; speedup vs baseline: 1.9375x; 1.9375x over previous
//
#include <hip/hip_runtime.h>
#include <math.h>

#define B 64
#define H 512
#define MAXN 512
#define U 512
#define MM 32
#define IN_SZ 543      // H + M - 1
#define DEC_STRIDE 544

// ---- d_out layout (floats) ----
#define PTR_OFF 0
#define PTR_SZ (B*MAXN*MM)            // 1,048,576
#define CLOSS_OFF (PTR_OFF + PTR_SZ)  // 1,048,576
#define ENC_OFF (CLOSS_OFF + 1)       // 1,048,577  (NOT 16B aligned -> scalar access to enc)
#define ENC_SZ (B*MAXN*H)             // 16,777,216
#define ADJ_OFF (ENC_OFF + ENC_SZ)    // 17,825,793

// ---- ws layout (floats) ----
#define EP_OFF 0
#define EP_SZ (B*MAXN*U)              // 16,777,216
#define HID0_OFF (EP_OFF + EP_SZ)
#define HID1_OFF (HID0_OFF + B*H)
#define COV_OFF  (HID1_OFF + B*H)
#define DEC_OFF  (COV_OFF + B*MAXN)
#define CL_OFF   (DEC_OFF + B*DEC_STRIDE)
#define OFFS_OFF (CL_OFF + 64)

__device__ __forceinline__ float tanh_fast(float x){
    float e = __builtin_amdgcn_exp2f(x * 2.885390081777927f);
    return 1.0f - 2.0f * __builtin_amdgcn_rcpf(e + 1.0f);
}

// ---------------- init ----------------
__global__ void k_init(float* __restrict__ ws, float* __restrict__ out,
                       const float* __restrict__ hg, const int* __restrict__ lengths){
    int gid = blockIdx.x*256 + threadIdx.x;
    int nth = gridDim.x*256;
    float* ptr = out + PTR_OFF;
    for (int i=gid;i<PTR_SZ;i+=nth) ptr[i]=0.f;
    float* dec = ws + DEC_OFF;
    for (int i=gid;i<B*DEC_STRIDE;i+=nth) dec[i]=0.f;
    float* cov = ws + COV_OFF;
    float* hid0 = ws + HID0_OFF;
    for (int i=gid;i<B*H;i+=nth){ cov[i]=0.f; hid0[i]=hg[i]; }
    if (gid<64) (ws+CL_OFF)[gid]=0.f;
    if (gid==0){
        int* offs=(int*)(ws+OFFS_OFF); int acc=0;
        for(int b=0;b<B;b++){ offs[b]=acc; acc+=lengths[b]; }
    }
}

// ---------------- gather enc ----------------
__global__ __launch_bounds__(256) void k_gather(const float* __restrict__ h,
        const int* __restrict__ lengths, const float* __restrict__ offs_f,
        float* __restrict__ enc){
    const int* offs = (const int*)offs_f;
    int t = threadIdx.x;
    int row = blockIdx.x*2 + (t>>7);
    int c = (t&127)*4;
    int b = row >> 9, n = row & 511;
    int len = lengths[b];
    float4 v = make_float4(0.f,0.f,0.f,0.f);
    if (n < len){
        const float* p = h + (size_t)(offs[b]+n)*H + c;
        v = *(const float4*)p;
    }
    float* q = enc + (size_t)row*H + c;
    q[0]=v.x; q[1]=v.y; q[2]=v.z; q[3]=v.w;
}

// ---------------- ep = enc @ W1^T, fp32 tiled 128x128 ----------------
__global__ __launch_bounds__(256) void k_gemm_ep(const float* __restrict__ enc,
        const float* __restrict__ W1, float* __restrict__ ep){
    __shared__ float As[16][132];
    __shared__ float Bs[16][132];
    int tid = threadIdx.x;
    int bm = blockIdx.x >> 2, bn = blockIdx.x & 3;
    int r0 = bm*128, u0 = bn*128;
    int ty = tid >> 4, tx = tid & 15;
    float acc[8][8];
#pragma unroll
    for (int i=0;i<8;i++){
#pragma unroll
        for(int j=0;j<8;j++) acc[i][j]=0.f;
    }
    for (int k0=0;k0<512;k0+=16){
#pragma unroll
        for (int it=0; it<8; ++it){
            int idx = tid + it*256;
            int row = idx >> 4, k = idx & 15;
            As[k][row] = enc[(size_t)(r0+row)*512 + k0 + k];
        }
#pragma unroll
        for (int it=0; it<2; ++it){
            int idx = tid + it*256;
            int nn = idx >> 2, c = idx & 3;
            float4 v = *(const float4*)&W1[(size_t)(u0+nn)*512 + k0 + c*4];
            Bs[c*4+0][nn]=v.x; Bs[c*4+1][nn]=v.y; Bs[c*4+2][nn]=v.z; Bs[c*4+3][nn]=v.w;
        }
        __syncthreads();
#pragma unroll
        for (int k=0;k<16;k++){
            float4 a0 = *(const float4*)&As[k][ty*8];
            float4 a1 = *(const float4*)&As[k][ty*8+4];
            float4 b0 = *(const float4*)&Bs[k][tx*4];
            float4 b1 = *(const float4*)&Bs[k][64+tx*4];
            float a[8]={a0.x,a0.y,a0.z,a0.w,a1.x,a1.y,a1.z,a1.w};
            float bb[8]={b0.x,b0.y,b0.z,b0.w,b1.x,b1.y,b1.z,b1.w};
#pragma unroll
            for(int im=0;im<8;im++){
#pragma unroll
                for(int jn=0;jn<8;jn++) acc[im][jn] += a[im]*bb[jn];
            }
        }
        __syncthreads();
    }
#pragma unroll
    for (int im=0;im<8;im++){
        int r = r0 + ty*8 + im;
        float4 v0 = make_float4(acc[im][0],acc[im][1],acc[im][2],acc[im][3]);
        float4 v1 = make_float4(acc[im][4],acc[im][5],acc[im][6],acc[im][7]);
        *(float4*)&ep[(size_t)r*512 + u0 + tx*4] = v0;
        *(float4*)&ep[(size_t)r*512 + u0 + 64 + tx*4] = v1;
    }
}

// ---------------- GRU (proven R1 version) ----------------
__global__ __launch_bounds__(256) void k_gru(const float* __restrict__ dec_in,
        const float* __restrict__ hid_in, float* __restrict__ hid_out,
        const float* __restrict__ w_ih, const float* __restrict__ w_hh,
        const float* __restrict__ b_ih, const float* __restrict__ b_hh){
    __shared__ float As[64][36];
    __shared__ float Ws[12][36];
    int tid=threadIdx.x; int b=tid&63; int q=tid>>6;
    int h0=blockIdx.x*4;
    float aI0=0,aI1=0,aI2=0,aH0=0,aH1=0,aH2=0;
    for (int k0=0;k0<IN_SZ;k0+=32){
        for (int it=0;it<2;it++){
            int idx=tid+it*256; int row=idx>>3, c=idx&7; int k=k0+c*4;
            float4 v=make_float4(0.f,0.f,0.f,0.f);
            const float* p=&dec_in[row*DEC_STRIDE+k];
            if (k+3 < IN_SZ) v=*(const float4*)p;
            else { if(k<IN_SZ)v.x=p[0]; if(k+1<IN_SZ)v.y=p[1]; if(k+2<IN_SZ)v.z=p[2]; }
            *(float4*)&As[row][c*4]=v;
        }
        if (tid<96){
            int rr=tid>>3,c=tid&7; int g=rr>>2,qq=rr&3;
            int j=h0+qq+512*g; int k=k0+c*4;
            float4 v=make_float4(0.f,0.f,0.f,0.f);
            const float* p=&w_ih[(size_t)j*IN_SZ+k];
            if(k<IN_SZ)v.x=p[0]; if(k+1<IN_SZ)v.y=p[1];
            if(k+2<IN_SZ)v.z=p[2]; if(k+3<IN_SZ)v.w=p[3];
            *(float4*)&Ws[rr][c*4]=v;
        }
        __syncthreads();
#pragma unroll
        for (int kk=0;kk<32;kk+=4){
            float4 a=*(const float4*)&As[b][kk];
            float4 w0=*(const float4*)&Ws[q][kk];
            float4 w1=*(const float4*)&Ws[4+q][kk];
            float4 w2=*(const float4*)&Ws[8+q][kk];
            aI0 += a.x*w0.x + a.y*w0.y + a.z*w0.z + a.w*w0.w;
            aI1 += a.x*w1.x + a.y*w1.y + a.z*w1.z + a.w*w1.w;
            aI2 += a.x*w2.x + a.y*w2.y + a.z*w2.z + a.w*w2.w;
        }
        __syncthreads();
    }
    for (int k0=0;k0<512;k0+=32){
        for (int it=0;it<2;it++){
            int idx=tid+it*256; int row=idx>>3,c=idx&7; int k=k0+c*4;
            *(float4*)&As[row][c*4] = *(const float4*)&hid_in[row*512+k];
        }
        if (tid<96){
            int rr=tid>>3,c=tid&7; int g=rr>>2,qq=rr&3;
            int j=h0+qq+512*g; int k=k0+c*4;
            *(float4*)&Ws[rr][c*4] = *(const float4*)&w_hh[(size_t)j*512+k];
        }
        __syncthreads();
#pragma unroll
        for (int kk=0;kk<32;kk+=4){
            float4 a=*(const float4*)&As[b][kk];
            float4 w0=*(const float4*)&Ws[q][kk];
            float4 w1=*(const float4*)&Ws[4+q][kk];
            float4 w2=*(const float4*)&Ws[8+q][kk];
            aH0 += a.x*w0.x + a.y*w0.y + a.z*w0.z + a.w*w0.w;
            aH1 += a.x*w1.x + a.y*w1.y + a.z*w1.z + a.w*w1.w;
            aH2 += a.x*w2.x + a.y*w2.y + a.z*w2.z + a.w*w2.w;
        }
        __syncthreads();
    }
    int h=h0+q;
    float gi0=aI0+b_ih[h], gi1=aI1+b_ih[h+512], gi2=aI2+b_ih[h+1024];
    float gh0=aH0+b_hh[h], gh1=aH1+b_hh[h+512], gh2=aH2+b_hh[h+1024];
    float r=1.f/(1.f+expf(-(gi0+gh0)));
    float z=1.f/(1.f+expf(-(gi1+gh1)));
    float nn=tanhf(gi2 + r*gh2);
    float hp=hid_in[b*512+h];
    hid_out[b*512+h]=(1.f-z)*nn+z*hp;
}

// ---------------- fused attention step: one block per b, 1024 threads ----------------
// w2h = hid[b]@W2^T ; theta -> dec tail + adj ; scores ; softmax/cov/closs/argmax/dec head
__global__ __launch_bounds__(1024) void k_att(
        const float* __restrict__ hid, const float* __restrict__ W2,
        const float* __restrict__ Wf, const float* __restrict__ bf,
        const float* __restrict__ wc, const float* __restrict__ v,
        const float* __restrict__ ep, const float* __restrict__ gum,
        const int* __restrict__ lengths, const float* __restrict__ enc,
        float* __restrict__ cov, float* __restrict__ dec_in,
        float* __restrict__ closs_b, float* __restrict__ pointer,
        float* __restrict__ adj, int step){
    __shared__ float sH[512];     // hid[b]
    __shared__ float sW[512];     // w2h
    __shared__ float sV[512];     // v
    __shared__ float sC[512];     // wc
    __shared__ float sCov[512];   // cov[b]
    __shared__ float sSc[512];    // scores
    __shared__ float red[512];
    __shared__ int  redi[512];
    const int b = blockIdx.x;
    const int tid = threadIdx.x;
    const int wave = tid >> 6, lane = tid & 63;
    const int len = lengths[b];

    {   // stage hid, v, wc, cov (4 arrays x 512 floats via 128 threads each)
        int seg = tid >> 7, off = (tid & 127) * 4;
        if (seg==0)      *(float4*)&sH[off]   = *(const float4*)&hid[b*512+off];
        else if (seg==1) *(float4*)&sV[off]   = *(const float4*)&v[off];
        else if (seg==2) *(float4*)&sC[off]   = *(const float4*)&wc[off];
        else if (seg==3) *(float4*)&sCov[off] = *(const float4*)&cov[b*512+off];
    }
    __syncthreads();

    // ---- w2h: wave handles u in [wave*32, wave*32+32); lane covers 8 k each ----
    {
        float4 h0 = *(const float4*)&sH[lane*8];
        float4 h1 = *(const float4*)&sH[lane*8+4];
#pragma unroll 4
        for (int u = wave*32; u < wave*32+32; ++u){
            const float4* wr = (const float4*)&W2[(size_t)u*512 + lane*8];
            float4 w0 = wr[0], w1 = wr[1];
            float acc = w0.x*h0.x + w0.y*h0.y + w0.z*h0.z + w0.w*h0.w
                      + w1.x*h1.x + w1.y*h1.y + w1.z*h1.z + w1.w*h1.w;
#pragma unroll
            for (int m=1;m<64;m<<=1) acc += __shfl_xor(acc, m, 64);
            if (lane==0) sW[u] = acc;
        }
        // theta rows (31), same pattern on Wf
        for (int u = wave; u < 31; u += 16){
            const float4* wr = (const float4*)&Wf[(size_t)u*512 + lane*8];
            float4 w0 = wr[0], w1 = wr[1];
            float acc = w0.x*h0.x + w0.y*h0.y + w0.z*h0.z + w0.w*h0.w
                      + w1.x*h1.x + w1.y*h1.y + w1.z*h1.z + w1.w*h1.w;
#pragma unroll
            for (int m=1;m<64;m<<=1) acc += __shfl_xor(acc, m, 64);
            if (lane==0){
                float th = 1.f/(1.f+expf(-(acc + bf[u])));
                th = (u < step) ? th : 0.f;
                dec_in[b*DEC_STRIDE + 512 + u] = th;
                adj[b*992 + u*32 + step] = th;
            }
        }
    }
    __syncthreads();

    // ---- scores: wave handles rows n = wave, wave+16, ... ----
    {
        float4 vv0 = *(const float4*)&sV[lane*8];
        float4 vv1 = *(const float4*)&sV[lane*8+4];
        float4 cc0 = *(const float4*)&sC[lane*8];
        float4 cc1 = *(const float4*)&sC[lane*8+4];
        float4 ww0 = *(const float4*)&sW[lane*8];
        float4 ww1 = *(const float4*)&sW[lane*8+4];
        for (int n = wave; n < len; n += 16){
            float cb = sCov[n];
            const float4* rr = (const float4*)&ep[((size_t)b*512+n)*512 + lane*8];
            float4 e0 = rr[0], e1 = rr[1];
            float acc;
            acc  = tanh_fast(e0.x + ww0.x + cb*cc0.x)*vv0.x;
            acc += tanh_fast(e0.y + ww0.y + cb*cc0.y)*vv0.y;
            acc += tanh_fast(e0.z + ww0.z + cb*cc0.z)*vv0.z;
            acc += tanh_fast(e0.w + ww0.w + cb*cc0.w)*vv0.w;
            acc += tanh_fast(e1.x + ww1.x + cb*cc1.x)*vv1.x;
            acc += tanh_fast(e1.y + ww1.y + cb*cc1.y)*vv1.y;
            acc += tanh_fast(e1.z + ww1.z + cb*cc1.z)*vv1.z;
            acc += tanh_fast(e1.w + ww1.w + cb*cc1.w)*vv1.w;
#pragma unroll
            for (int m=1;m<64;m<<=1) acc += __shfl_xor(acc, m, 64);
            if (lane==0) sSc[n] = acc;
        }
    }
    __syncthreads();

    // ---- softmax / coverage / closs / argmax / dec head ----
    int n = tid;                        // threads 0..511 active per-element
    float e = 0.f;
    if (n < 512) e = (n < len) ? expf(sSc[n]) : 0.f;
    if (n < 512) red[n] = e;
    __syncthreads();
    for (int o=256;o>=1;o>>=1){ if (n<o) red[n]+=red[n+o]; __syncthreads(); }
    float Z = red[0];
    __syncthreads();
    float att = 0.f, cvo = 0.f;
    if (n < 512){
        att = e / Z;
        cvo = sCov[n];
        red[n] = fminf(att, cvo);
    }
    __syncthreads();
    for (int o=256;o>=1;o>>=1){ if (n<o) red[n]+=red[n+o]; __syncthreads(); }
    if (tid==0) closs_b[b] += red[0];
    __syncthreads();
    float lg = 0.f;
    if (n < 512){
        cov[b*512+n] = cvo + att;
        lg = logf(att + 1e-12f) + gum[((size_t)step*64+b)*512 + n];
        red[n] = lg; redi[n] = n;
    }
    __syncthreads();
    for (int o=256;o>=1;o>>=1){
        if (n<o && red[n+o]>red[n]){ red[n]=red[n+o]; redi[n]=redi[n+o]; }
        __syncthreads();
    }
    int ns = redi[0];
    if (tid==0) pointer[b*16384 + ns*32 + step] = 1.f;
    if (n < 512) dec_in[b*DEC_STRIDE + n] = enc[((size_t)b*512+ns)*512 + n];
}

__global__ void k_final(const float* __restrict__ closs_b, float* __restrict__ out){
    if (threadIdx.x==0 && blockIdx.x==0){
        float s=0.f;
        for(int b=0;b<B;b++) s+=closs_b[b];
        out[CLOSS_OFF]=s/64.f;
    }
}

extern "C" void kernel_launch(void* const* d_in, const int* in_sizes, int n_in,
                              void* d_out, int out_size, void* d_ws, size_t ws_size,
                              hipStream_t stream){
    const float* h      = (const float*)d_in[0];
    const float* hg     = (const float*)d_in[1];
    const int*   lengths= (const int*)  d_in[2];
    const float* gumbel = (const float*)d_in[3];
    const float* W1     = (const float*)d_in[4];
    const float* W2     = (const float*)d_in[5];
    const float* wc     = (const float*)d_in[6];
    const float* v      = (const float*)d_in[7];
    const float* w_ih   = (const float*)d_in[8];
    const float* w_hh   = (const float*)d_in[9];
    const float* b_ih   = (const float*)d_in[10];
    const float* b_hh   = (const float*)d_in[11];
    const float* Wf     = (const float*)d_in[12];
    const float* bf     = (const float*)d_in[13];
    float* out = (float*)d_out;
    float* ws  = (float*)d_ws;
    float* enc = out + ENC_OFF;
    float* adj = out + ADJ_OFF;
    float* pointer = out + PTR_OFF;
    float* ep   = ws + EP_OFF;
    float* hidA = ws + HID0_OFF;
    float* hidB = ws + HID1_OFF;
    float* cov  = ws + COV_OFF;
    float* dec  = ws + DEC_OFF;
    float* clb  = ws + CL_OFF;

    hipLaunchKernelGGL(k_init,   dim3(512),  dim3(256), 0, stream, ws, out, hg, lengths);
    hipLaunchKernelGGL(k_gather, dim3(16384),dim3(256), 0, stream, h, lengths, ws+OFFS_OFF, enc);
    hipLaunchKernelGGL(k_gemm_ep,dim3(1024), dim3(256), 0, stream, enc, W1, ep);

    for (int i=0;i<MM;i++){
        const float* hin = (i&1)? hidB : hidA;
        float*       hout= (i&1)? hidA : hidB;
        hipLaunchKernelGGL(k_gru, dim3(128), dim3(256), 0, stream,
                           dec, hin, hout, w_ih, w_hh, b_ih, b_hh);
        hipLaunchKernelGGL(k_att, dim3(64), dim3(1024), 0, stream,
                           hout, W2, Wf, bf, wc, v, ep, gumbel, lengths, enc,
                           cov, dec, clb, pointer, adj, i);
    }
    hipLaunchKernelGGL(k_final, dim3(1), dim3(64), 0, stream, clb, out);
}

// Round 5
// 1848.216 us; speedup vs baseline: 3.3852x; 1.7472x over previous
//
#include <hip/hip_runtime.h>
#include <math.h>

#define B 64
#define H 512
#define MAXN 512
#define U 512
#define MM 32
#define IN_SZ 543      // H + M - 1
#define DEC_STRIDE 544

// ---- d_out layout (floats) ----
#define PTR_OFF 0
#define PTR_SZ (B*MAXN*MM)            // 1,048,576
#define CLOSS_OFF (PTR_OFF + PTR_SZ)  // 1,048,576
#define ENC_OFF (CLOSS_OFF + 1)       // 1,048,577  (NOT 16B aligned)
#define ENC_SZ (B*MAXN*H)             // 16,777,216
#define ADJ_OFF (ENC_OFF + ENC_SZ)    // 17,825,793

// ---- ws layout (floats) ----
#define EP_OFF 0
#define EP_SZ (B*MAXN*U)              // 16,777,216
#define GP_OFF (EP_OFF + EP_SZ)
#define GP_SZ (4*3*B*H)               // 393,216  (slice s, gate g, b, h)
#define HID0_OFF (GP_OFF + GP_SZ)
#define HID1_OFF (HID0_OFF + B*H)
#define W2H_OFF  (HID1_OFF + B*H)
#define COV_OFF  (W2H_OFF + B*H)
#define SC_OFF   (COV_OFF + B*MAXN)
#define DEC_OFF  (SC_OFF + B*MAXN)
#define CL_OFF   (DEC_OFF + B*DEC_STRIDE)
#define OFFS_OFF (CL_OFF + 64)

__device__ __forceinline__ float tanh_fast(float x){
    float e = __builtin_amdgcn_exp2f(x * 2.885390081777927f);
    return 1.0f - 2.0f * __builtin_amdgcn_rcpf(e + 1.0f);
}

// ---------------- init ----------------
__global__ void k_init(float* __restrict__ ws, float* __restrict__ out,
                       const float* __restrict__ hg, const int* __restrict__ lengths){
    int gid = blockIdx.x*256 + threadIdx.x;
    int nth = gridDim.x*256;
    float* ptr = out + PTR_OFF;
    for (int i=gid;i<PTR_SZ;i+=nth) ptr[i]=0.f;
    float* dec = ws + DEC_OFF;
    for (int i=gid;i<B*DEC_STRIDE;i+=nth) dec[i]=0.f;
    float* cov = ws + COV_OFF;
    float* hid0 = ws + HID0_OFF;
    for (int i=gid;i<B*H;i+=nth){ cov[i]=0.f; hid0[i]=hg[i]; }
    if (gid<64) (ws+CL_OFF)[gid]=0.f;
    if (gid==0){
        int* offs=(int*)(ws+OFFS_OFF); int acc=0;
        for(int b=0;b<B;b++){ offs[b]=acc; acc+=lengths[b]; }
    }
}

// ---------------- gather enc ----------------
__global__ __launch_bounds__(256) void k_gather(const float* __restrict__ h,
        const int* __restrict__ lengths, const float* __restrict__ offs_f,
        float* __restrict__ enc){
    const int* offs = (const int*)offs_f;
    int t = threadIdx.x;
    int row = blockIdx.x*2 + (t>>7);
    int c = (t&127)*4;
    int b = row >> 9, n = row & 511;
    int len = lengths[b];
    float4 v = make_float4(0.f,0.f,0.f,0.f);
    if (n < len){
        const float* p = h + (size_t)(offs[b]+n)*H + c;
        v = *(const float4*)p;
    }
    float* q = enc + (size_t)row*H + c;
    q[0]=v.x; q[1]=v.y; q[2]=v.z; q[3]=v.w;
}

// ---------------- ep = enc @ W1^T, fp32 tiled 128x128 ----------------
__global__ __launch_bounds__(256) void k_gemm_ep(const float* __restrict__ enc,
        const float* __restrict__ W1, float* __restrict__ ep){
    __shared__ float As[16][132];
    __shared__ float Bs[16][132];
    int tid = threadIdx.x;
    int bm = blockIdx.x >> 2, bn = blockIdx.x & 3;
    int r0 = bm*128, u0 = bn*128;
    int ty = tid >> 4, tx = tid & 15;
    float acc[8][8];
#pragma unroll
    for (int i=0;i<8;i++){
#pragma unroll
        for(int j=0;j<8;j++) acc[i][j]=0.f;
    }
    for (int k0=0;k0<512;k0+=16){
#pragma unroll
        for (int it=0; it<8; ++it){
            int idx = tid + it*256;
            int row = idx >> 4, k = idx & 15;
            As[k][row] = enc[(size_t)(r0+row)*512 + k0 + k];
        }
#pragma unroll
        for (int it=0; it<2; ++it){
            int idx = tid + it*256;
            int nn = idx >> 2, c = idx & 3;
            float4 v = *(const float4*)&W1[(size_t)(u0+nn)*512 + k0 + c*4];
            Bs[c*4+0][nn]=v.x; Bs[c*4+1][nn]=v.y; Bs[c*4+2][nn]=v.z; Bs[c*4+3][nn]=v.w;
        }
        __syncthreads();
#pragma unroll
        for (int k=0;k<16;k++){
            float4 a0 = *(const float4*)&As[k][ty*8];
            float4 a1 = *(const float4*)&As[k][ty*8+4];
            float4 b0 = *(const float4*)&Bs[k][tx*4];
            float4 b1 = *(const float4*)&Bs[k][64+tx*4];
            float a[8]={a0.x,a0.y,a0.z,a0.w,a1.x,a1.y,a1.z,a1.w};
            float bb[8]={b0.x,b0.y,b0.z,b0.w,b1.x,b1.y,b1.z,b1.w};
#pragma unroll
            for(int im=0;im<8;im++){
#pragma unroll
                for(int jn=0;jn<8;jn++) acc[im][jn] += a[im]*bb[jn];
            }
        }
        __syncthreads();
    }
#pragma unroll
    for (int im=0;im<8;im++){
        int r = r0 + ty*8 + im;
        float4 v0 = make_float4(acc[im][0],acc[im][1],acc[im][2],acc[im][3]);
        float4 v1 = make_float4(acc[im][4],acc[im][5],acc[im][6],acc[im][7]);
        *(float4*)&ep[(size_t)r*512 + u0 + tx*4] = v0;
        *(float4*)&ep[(size_t)r*512 + u0 + 64 + tx*4] = v1;
    }
}

// ---------------- GRU partial dots: 512 blocks, 4-way K-split ----------------
// block = (s, h-chunk of 4); s: 0=ih[0,288) 1=ih[288,543) 2=hh[0,256) 3=hh[256,512)
// thread (b=tid&63, q=tid>>6): 3 gate-partials for (b, h0+q)
__global__ __launch_bounds__(256) void k_gruP(const float* __restrict__ dec_in,
        const float* __restrict__ hid_in,
        const float* __restrict__ w_ih, const float* __restrict__ w_hh,
        float* __restrict__ gp){
    __shared__ float As[64][36];
    __shared__ float Ws[12][36];
    int tid=threadIdx.x, b=tid&63, q=tid>>6;
    int s = blockIdx.x >> 7;
    int h0 = (int)(blockIdx.x & 127) * 4;
    const float* xs; int xstride, kbeg, kend; const float* W; int wstride;
    if (s==0){ xs=dec_in; xstride=DEC_STRIDE; kbeg=0;   kend=288;   W=w_ih; wstride=IN_SZ; }
    else if(s==1){ xs=dec_in; xstride=DEC_STRIDE; kbeg=288; kend=IN_SZ; W=w_ih; wstride=IN_SZ; }
    else if(s==2){ xs=hid_in; xstride=512; kbeg=0;   kend=256; W=w_hh; wstride=512; }
    else         { xs=hid_in; xstride=512; kbeg=256; kend=512; W=w_hh; wstride=512; }
    float a0=0.f,a1=0.f,a2=0.f;
    for (int k0=kbeg; k0<kend; k0+=32){
        // stage x slice: 64 rows x 32 k
        for (int it=0;it<2;it++){
            int idx=tid+it*256; int row=idx>>3, c=idx&7; int k=k0+c*4;
            float4 v=make_float4(0.f,0.f,0.f,0.f);
            const float* p=&xs[row*xstride+k];
            if (k+3 < kend) v=*(const float4*)p;
            else { if(k<kend)v.x=p[0]; if(k+1<kend)v.y=p[1]; if(k+2<kend)v.z=p[2]; }
            *(float4*)&As[row][c*4]=v;
        }
        // stage 12 weight rows x 32 k
        if (tid<96){
            int rr=tid>>3, c=tid&7; int g=rr>>2, qq=rr&3;
            int j=g*512 + h0+qq; int k=k0+c*4;
            float4 v=make_float4(0.f,0.f,0.f,0.f);
            const float* p=&W[(size_t)j*wstride+k];
            if (wstride==512){
                v=*(const float4*)p;   // aligned, k+3<kend always (kend mult of 32)
            } else {
                if(k<kend)v.x=p[0]; if(k+1<kend)v.y=p[1];
                if(k+2<kend)v.z=p[2]; if(k+3<kend)v.w=p[3];
            }
            *(float4*)&Ws[rr][c*4]=v;
        }
        __syncthreads();
#pragma unroll
        for (int kk=0;kk<32;kk+=4){
            float4 a=*(const float4*)&As[b][kk];
            float4 w0=*(const float4*)&Ws[q][kk];
            float4 w1=*(const float4*)&Ws[4+q][kk];
            float4 w2=*(const float4*)&Ws[8+q][kk];
            a0 += a.x*w0.x + a.y*w0.y + a.z*w0.z + a.w*w0.w;
            a1 += a.x*w1.x + a.y*w1.y + a.z*w1.z + a.w*w1.w;
            a2 += a.x*w2.x + a.y*w2.y + a.z*w2.z + a.w*w2.w;
        }
        __syncthreads();
    }
    int h = h0 + q;
    gp[((s*3+0)*64+b)*512 + h] = a0;
    gp[((s*3+1)*64+b)*512 + h] = a1;
    gp[((s*3+2)*64+b)*512 + h] = a2;
}

// ---------------- mid: GRU epilogue + w2h (u-chunk) + theta ----------------
// 256 blocks = (b, uc of 4); 512 threads
__global__ __launch_bounds__(512) void k_mid(const float* __restrict__ gp,
        const float* __restrict__ hid_in, float* __restrict__ hid_out,
        const float* __restrict__ b_ih, const float* __restrict__ b_hh,
        const float* __restrict__ W2, const float* __restrict__ Wf,
        const float* __restrict__ bf,
        float* __restrict__ w2h, float* __restrict__ dec_in,
        float* __restrict__ adj, int step){
    __shared__ float sH[512];
    int b = blockIdx.x >> 2, uc = blockIdx.x & 3;
    int tid = threadIdx.x;
    {   // GRU epilogue for h = tid (redundant across uc — cheap)
        int h = tid;
        float gI0 = gp[((0*3+0)*64+b)*512+h] + gp[((1*3+0)*64+b)*512+h];
        float gI1 = gp[((0*3+1)*64+b)*512+h] + gp[((1*3+1)*64+b)*512+h];
        float gI2 = gp[((0*3+2)*64+b)*512+h] + gp[((1*3+2)*64+b)*512+h];
        float gH0 = gp[((2*3+0)*64+b)*512+h] + gp[((3*3+0)*64+b)*512+h];
        float gH1 = gp[((2*3+1)*64+b)*512+h] + gp[((3*3+1)*64+b)*512+h];
        float gH2 = gp[((2*3+2)*64+b)*512+h] + gp[((3*3+2)*64+b)*512+h];
        float gi0=gI0+b_ih[h],     gh0=gH0+b_hh[h];
        float gi1=gI1+b_ih[512+h], gh1=gH1+b_hh[512+h];
        float gi2=gI2+b_ih[1024+h],gh2=gH2+b_hh[1024+h];
        float r=1.f/(1.f+expf(-(gi0+gh0)));
        float z=1.f/(1.f+expf(-(gi1+gh1)));
        float nn=tanhf(gi2 + r*gh2);
        float hv=(1.f-z)*nn + z*hid_in[b*512+h];
        sH[h]=hv;
        if (uc==0) hid_out[b*512+h]=hv;
    }
    __syncthreads();
    int wv=tid>>6, lane=tid&63;
    // w2h for u-chunk [uc*128, uc*128+128)
    for (int ul=wv; ul<128; ul+=8){
        int u = uc*128 + ul;
        const float* wr = &W2[(size_t)u*512];
        float acc=0.f;
#pragma unroll
        for (int t=0;t<8;t++){ int k=t*64+lane; acc += wr[k]*sH[k]; }
#pragma unroll
        for (int m=1;m<64;m<<=1) acc += __shfl_xor(acc, m, 64);
        if (lane==0) w2h[b*512+u]=acc;
    }
    // theta (uc==0 only)
    if (uc==0){
        for (int ul=wv; ul<31; ul+=8){
            const float* wr = &Wf[(size_t)ul*512];
            float acc=0.f;
#pragma unroll
            for (int t=0;t<8;t++){ int k=t*64+lane; acc += wr[k]*sH[k]; }
#pragma unroll
            for (int m=1;m<64;m<<=1) acc += __shfl_xor(acc, m, 64);
            if (lane==0){
                float th = 1.f/(1.f+expf(-(acc + bf[ul])));
                th = (ul < step) ? th : 0.f;
                dec_in[b*DEC_STRIDE + 512 + ul] = th;
                adj[b*992 + ul*32 + step] = th;
            }
        }
    }
}

// ---------------- scores: 1024 blocks = (b, nc of 16), 256 threads ----------------
__global__ __launch_bounds__(256) void k_scores(const float* __restrict__ ep,
        const float* __restrict__ w2h, const float* __restrict__ cov,
        const float* __restrict__ wc, const float* __restrict__ v,
        const int* __restrict__ lengths, float* __restrict__ sc){
    __shared__ float sW[512], sV[512], sC[512];
    int b = blockIdx.x >> 4, nc = blockIdx.x & 15;
    int len = lengths[b];
    if (nc*32 >= len) return;
    int tid=threadIdx.x;
    for (int idx=tid; idx<384; idx+=256){
        int which = idx>>7, c = (idx&127)*4;
        float4 val;
        if (which==0) val=*(const float4*)&w2h[b*512+c];
        else if (which==1) val=*(const float4*)&v[c];
        else val=*(const float4*)&wc[c];
        float* dst = (which==0)?sW:((which==1)?sV:sC);
        *(float4*)&dst[c]=val;
    }
    __syncthreads();
    int wv=tid>>6, lane=tid&63;
    float4 vv0=*(const float4*)&sV[lane*8], vv1=*(const float4*)&sV[lane*8+4];
    float4 cc0=*(const float4*)&sC[lane*8], cc1=*(const float4*)&sC[lane*8+4];
    float4 ww0=*(const float4*)&sW[lane*8], ww1=*(const float4*)&sW[lane*8+4];
#pragma unroll
    for (int r=0;r<8;r++){
        int n = nc*32 + wv*8 + r;
        float cb = cov[b*512+n];
        const float4* rr = (const float4*)&ep[((size_t)b*512+n)*512 + lane*8];
        float4 e0=rr[0], e1=rr[1];
        float acc;
        acc  = tanh_fast(e0.x + ww0.x + cb*cc0.x)*vv0.x;
        acc += tanh_fast(e0.y + ww0.y + cb*cc0.y)*vv0.y;
        acc += tanh_fast(e0.z + ww0.z + cb*cc0.z)*vv0.z;
        acc += tanh_fast(e0.w + ww0.w + cb*cc0.w)*vv0.w;
        acc += tanh_fast(e1.x + ww1.x + cb*cc1.x)*vv1.x;
        acc += tanh_fast(e1.y + ww1.y + cb*cc1.y)*vv1.y;
        acc += tanh_fast(e1.z + ww1.z + cb*cc1.z)*vv1.z;
        acc += tanh_fast(e1.w + ww1.w + cb*cc1.w)*vv1.w;
#pragma unroll
        for (int m=1;m<64;m<<=1) acc += __shfl_xor(acc, m, 64);
        if (lane==0) sc[b*512+n]=acc;
    }
}

// ---------------- soft: 64 blocks x 512 (no-max-shift, validated R4) ----------------
__global__ __launch_bounds__(512) void k_soft(const float* __restrict__ sc,
        const float* __restrict__ gum, const int* __restrict__ lengths,
        const float* __restrict__ enc, float* __restrict__ cov,
        float* __restrict__ dec_in, float* __restrict__ closs_b,
        float* __restrict__ pointer, int step){
    __shared__ float red[512];
    __shared__ int  redi[512];
    int b=blockIdx.x, n=threadIdx.x;
    int len=lengths[b];
    float e = (n<len)? expf(sc[b*512+n]) : 0.f;
    red[n]=e; __syncthreads();
    for(int o=256;o>=1;o>>=1){ if(n<o) red[n]+=red[n+o]; __syncthreads(); }
    float Z=red[0]; __syncthreads();
    float att=e/Z;
    float c=cov[b*512+n];
    red[n]=fminf(att,c); __syncthreads();
    for(int o=256;o>=1;o>>=1){ if(n<o) red[n]+=red[n+o]; __syncthreads(); }
    if(n==0) closs_b[b]+=red[0];
    __syncthreads();
    cov[b*512+n]=c+att;
    float lg=logf(att+1e-12f)+gum[((size_t)step*64+b)*512+n];
    red[n]=lg; redi[n]=n; __syncthreads();
    for(int o=256;o>=1;o>>=1){
        if(n<o && red[n+o]>red[n]){ red[n]=red[n+o]; redi[n]=redi[n+o]; }
        __syncthreads();
    }
    int ns=redi[0];
    if(n==0) pointer[b*16384 + ns*32 + step]=1.f;
    dec_in[b*DEC_STRIDE+n]=enc[((size_t)b*512+ns)*512+n];
}

__global__ void k_final(const float* __restrict__ closs_b, float* __restrict__ out){
    if (threadIdx.x==0 && blockIdx.x==0){
        float s=0.f;
        for(int b=0;b<B;b++) s+=closs_b[b];
        out[CLOSS_OFF]=s/64.f;
    }
}

extern "C" void kernel_launch(void* const* d_in, const int* in_sizes, int n_in,
                              void* d_out, int out_size, void* d_ws, size_t ws_size,
                              hipStream_t stream){
    const float* h      = (const float*)d_in[0];
    const float* hg     = (const float*)d_in[1];
    const int*   lengths= (const int*)  d_in[2];
    const float* gumbel = (const float*)d_in[3];
    const float* W1     = (const float*)d_in[4];
    const float* W2     = (const float*)d_in[5];
    const float* wc     = (const float*)d_in[6];
    const float* v      = (const float*)d_in[7];
    const float* w_ih   = (const float*)d_in[8];
    const float* w_hh   = (const float*)d_in[9];
    const float* b_ih   = (const float*)d_in[10];
    const float* b_hh   = (const float*)d_in[11];
    const float* Wf     = (const float*)d_in[12];
    const float* bf     = (const float*)d_in[13];
    float* out = (float*)d_out;
    float* ws  = (float*)d_ws;
    float* enc = out + ENC_OFF;
    float* adj = out + ADJ_OFF;
    float* pointer = out + PTR_OFF;
    float* ep   = ws + EP_OFF;
    float* gp   = ws + GP_OFF;
    float* hidA = ws + HID0_OFF;
    float* hidB = ws + HID1_OFF;
    float* w2h  = ws + W2H_OFF;
    float* cov  = ws + COV_OFF;
    float* sc   = ws + SC_OFF;
    float* dec  = ws + DEC_OFF;
    float* clb  = ws + CL_OFF;

    hipLaunchKernelGGL(k_init,   dim3(512),  dim3(256), 0, stream, ws, out, hg, lengths);
    hipLaunchKernelGGL(k_gather, dim3(16384),dim3(256), 0, stream, h, lengths, ws+OFFS_OFF, enc);
    hipLaunchKernelGGL(k_gemm_ep,dim3(1024), dim3(256), 0, stream, enc, W1, ep);

    for (int i=0;i<MM;i++){
        const float* hin = (i&1)? hidB : hidA;
        float*       hout= (i&1)? hidA : hidB;
        hipLaunchKernelGGL(k_gruP,   dim3(512),  dim3(256), 0, stream,
                           dec, hin, w_ih, w_hh, gp);
        hipLaunchKernelGGL(k_mid,    dim3(256),  dim3(512), 0, stream,
                           gp, hin, hout, b_ih, b_hh, W2, Wf, bf, w2h, dec, adj, i);
        hipLaunchKernelGGL(k_scores, dim3(1024), dim3(256), 0, stream,
                           ep, w2h, cov, wc, v, lengths, sc);
        hipLaunchKernelGGL(k_soft,   dim3(64),   dim3(512), 0, stream,
                           sc, gumbel, lengths, enc, cov, dec, clb, pointer, i);
    }
    hipLaunchKernelGGL(k_final, dim3(1), dim3(64), 0, stream, clb, out);
}